// Round 2
// baseline (113.221 us; speedup 1.0000x reference)
//
#include <hip/hip_runtime.h>
#include <math.h>

#define N1 8192
#define N2 4096
#define N3 2048

// ---------- Kernel 1: l1 = 0.95*l1_state + 0.05*tanh(smi); also zero the counter ----------
__global__ __launch_bounds__(256) void k_l1(const float* __restrict__ smi,
                                            const float* __restrict__ l1s,
                                            float* __restrict__ l1,
                                            unsigned* __restrict__ counter) {
    int i = blockIdx.x * 256 + threadIdx.x;
    if (i == 0) *counter = 0u;  // visible to k_l3 via kernel-boundary ordering
    if (i < N1) l1[i] = 0.95f * l1s[i] + 0.05f * tanhf(smi[i]);
}

// ---------- Kernel 2: one block per row of w12/w32 ----------
__global__ __launch_bounds__(256) void k_l2(const float* __restrict__ w12,
                                            const float* __restrict__ w32,
                                            const float* __restrict__ l1,
                                            const float* __restrict__ l3s,
                                            const float* __restrict__ l2s,
                                            float* __restrict__ l2) {
    __shared__ float ws[4];
    const int r = blockIdx.x;
    const int t = threadIdx.x;
    const float4* __restrict__ w12r = reinterpret_cast<const float4*>(w12) + (size_t)r * (N1 / 4);
    const float4* __restrict__ w32r = reinterpret_cast<const float4*>(w32) + (size_t)r * (N3 / 4);
    const float4* __restrict__ x1 = reinterpret_cast<const float4*>(l1);
    const float4* __restrict__ x3 = reinterpret_cast<const float4*>(l3s);

    float acc = 0.0f;
#pragma unroll
    for (int k = 0; k < (N1 / 4) / 256; ++k) {  // 8 iters
        const int i = t + k * 256;
        float4 a = w12r[i];
        float4 b = x1[i];
        acc = fmaf(a.x, b.x, fmaf(a.y, b.y, fmaf(a.z, b.z, fmaf(a.w, b.w, acc))));
    }
    float acc2 = 0.0f;
#pragma unroll
    for (int k = 0; k < (N3 / 4) / 256; ++k) {  // 2 iters
        const int i = t + k * 256;
        float4 a = w32r[i];
        float4 b = x3[i];
        acc2 = fmaf(a.x, b.x, fmaf(a.y, b.y, fmaf(a.z, b.z, fmaf(a.w, b.w, acc2))));
    }
    float v = fmaf(0.3f, acc2, acc);
#pragma unroll
    for (int off = 32; off; off >>= 1) v += __shfl_down(v, off, 64);
    if ((t & 63) == 0) ws[t >> 6] = v;
    __syncthreads();
    if (t == 0) {
        float tot = ws[0] + ws[1] + ws[2] + ws[3];
        l2[r] = 0.98f * l2s[r] + 0.02f * tanhf(tot);
    }
}

// ---------- Kernel 3: one block per row of w23; LAST block computes all scalars ----------
__global__ __launch_bounds__(256) void k_l3(const float* __restrict__ w23,
                                            const float* __restrict__ out,  // [l1 | l2 | l3 | scal]
                                            const float* __restrict__ l3s,
                                            const float* __restrict__ corr_in,
                                            const float* __restrict__ coh_in,
                                            unsigned* __restrict__ counter) {
    __shared__ float wsum[4];
    __shared__ double red[4 * 13 + 13];
    __shared__ bool isLast;
    const int r = blockIdx.x;
    const int t = threadIdx.x;
    const float* l1 = out;
    const float* l2 = out + N1;
    float* l3 = (float*)out + N1 + N2;
    float* scal = l3 + N3;

    // ---- matvec: l3[r] = 0.99*l3s[r] + 0.01*tanh(w23[r,:]@l2) ----
    const float4* __restrict__ wr = reinterpret_cast<const float4*>(w23) + (size_t)r * (N2 / 4);
    const float4* __restrict__ x2 = reinterpret_cast<const float4*>(l2);
    float acc = 0.0f;
#pragma unroll
    for (int k = 0; k < (N2 / 4) / 256; ++k) {  // 4 iters
        const int i = t + k * 256;
        float4 a = wr[i];
        float4 b = x2[i];
        acc = fmaf(a.x, b.x, fmaf(a.y, b.y, fmaf(a.z, b.z, fmaf(a.w, b.w, acc))));
    }
    float v = acc;
#pragma unroll
    for (int off = 32; off; off >>= 1) v += __shfl_down(v, off, 64);
    if ((t & 63) == 0) wsum[t >> 6] = v;
    __syncthreads();
    if (t == 0) {
        float tot = wsum[0] + wsum[1] + wsum[2] + wsum[3];
        l3[r] = 0.99f * l3s[r] + 0.01f * tanhf(tot);
        __threadfence();  // release l3[r] to device scope before signaling
        unsigned prev = atomicAdd(counter, 1u);
        isLast = (prev == gridDim.x - 1);
    }
    __syncthreads();
    if (!isLast) return;

    // ---- last block: acquire other blocks' l3 writes ----
    __threadfence();

    // moments: [0]=sum|v| [1]=sum v [2]=sum v^2 over concat(l1,l2,l3)
    //          [3..7]  = sx,sy,sxx,syy,sxy over (l1[:4096], l2)
    //          [8..12] = sx,sy,sxx,syy,sxy over (l2[:2048], l3)
    double p[13];
#pragma unroll
    for (int j = 0; j < 13; ++j) p[j] = 0.0;

    for (int i = t; i < N1 + N2 + N3; i += 256) {
        double vv = (double)out[i];
        p[0] += fabs(vv);
        p[1] += vv;
        p[2] += vv * vv;
    }
    for (int i = t; i < N2; i += 256) {
        double x = (double)l1[i], y = (double)l2[i];
        p[3] += x; p[4] += y; p[5] += x * x; p[6] += y * y; p[7] += x * y;
    }
    for (int i = t; i < N3; i += 256) {
        double x = (double)l2[i], y = (double)l3[i];
        p[8] += x; p[9] += y; p[10] += x * x; p[11] += y * y; p[12] += x * y;
    }

    // 13 wave-level reductions, no barriers between them
#pragma unroll
    for (int j = 0; j < 13; ++j) {
        double vv = p[j];
#pragma unroll
        for (int off = 32; off; off >>= 1) vv += __shfl_down(vv, off, 64);
        p[j] = vv;
    }
    if ((t & 63) == 0) {
        const int w = t >> 6;
#pragma unroll
        for (int j = 0; j < 13; ++j) red[w * 13 + j] = p[j];
    }
    __syncthreads();
    if (t < 13) red[52 + t] = red[t] + red[13 + t] + red[26 + t] + red[39 + t];
    __syncthreads();

    if (t == 0) {
        const double* rr = red + 52;
        const double n12 = (double)N2;
        const double n23 = (double)N3;
        const double nall = (double)(N1 + N2 + N3);

        double sxy12 = rr[7] - rr[3] * rr[4] / n12;
        double sxx12 = rr[5] - rr[3] * rr[3] / n12;
        double syy12 = rr[6] - rr[4] * rr[4] / n12;
        double den12 = sqrt(sxx12 * syy12);
        double c12 = (den12 > 0.0 && isfinite(den12)) ? sxy12 / den12 : 0.0;

        double sxy23 = rr[12] - rr[8] * rr[9] / n23;
        double sxx23 = rr[10] - rr[8] * rr[8] / n23;
        double syy23 = rr[11] - rr[9] * rr[9] / n23;
        double den23 = sqrt(sxx23 * syy23);
        double c23 = (den23 > 0.0 && isfinite(den23)) ? sxy23 / den23 : 0.0;

        double corr_new = 0.9 * (double)corr_in[0] + 0.1 * (c12 + c23) * 0.5;

        double total = rr[0];
        double var = (rr[2] - rr[1] * rr[1] / nall) / (nall - 1.0);
        double coh = total / (var + 1e-6);
        coh = fmin(fmax(coh, 0.0), 10.0);
        double coh_new = 0.9 * (double)coh_in[0] + 0.1 * coh;

        scal[0] = (float)corr_new;
        scal[1] = (float)coh_new;
        scal[2] = (float)(total / nall);
    }
}

extern "C" void kernel_launch(void* const* d_in, const int* in_sizes, int n_in,
                              void* d_out, int out_size, void* d_ws, size_t ws_size,
                              hipStream_t stream) {
    const float* smi     = (const float*)d_in[0];
    const float* l1s     = (const float*)d_in[1];
    const float* l2s     = (const float*)d_in[2];
    const float* l3s     = (const float*)d_in[3];
    const float* w12     = (const float*)d_in[4];
    const float* w23     = (const float*)d_in[5];
    const float* w32     = (const float*)d_in[6];
    // d_in[7] = w21 is UNUSED by the reference — never read (saves 134 MB).
    const float* corr_in = (const float*)d_in[8];
    const float* coh_in  = (const float*)d_in[9];

    float* out = (float*)d_out;
    float* l1 = out;
    float* l2 = out + N1;
    unsigned* counter = (unsigned*)d_ws;

    k_l1<<<dim3(N1 / 256), dim3(256), 0, stream>>>(smi, l1s, l1, counter);
    k_l2<<<dim3(N2), dim3(256), 0, stream>>>(w12, w32, l1, l3s, l2s, l2);
    k_l3<<<dim3(N3), dim3(256), 0, stream>>>(w23, out, l3s, corr_in, coh_in, counter);
}

// Round 3
// 49.920 us; speedup vs baseline: 2.2680x; 2.2680x over previous
//
#include <hip/hip_runtime.h>
#include <math.h>

#define N1 8192
#define N2 4096
#define N3 2048

typedef float f4 __attribute__((ext_vector_type(4)));

// ---------- Kernel 1: l1 = 0.95*l1_state + 0.05*tanh(smi) ----------
__global__ __launch_bounds__(256) void k_l1(const float* __restrict__ smi,
                                            const float* __restrict__ l1s,
                                            float* __restrict__ l1) {
    int i = blockIdx.x * 256 + threadIdx.x;
    if (i < N1) l1[i] = 0.95f * l1s[i] + 0.05f * tanhf(smi[i]);
}

// ---------- Kernel 2: TWO rows of w12/w32 per block ----------
// l2[r] = 0.98*l2_state[r] + 0.02*tanh( w12[r,:]@l1 + 0.3*(w32[r,:]@l3_state) )
__global__ __launch_bounds__(256) void k_l2(const float* __restrict__ w12,
                                            const float* __restrict__ w32,
                                            const float* __restrict__ l1,
                                            const float* __restrict__ l3s,
                                            const float* __restrict__ l2s,
                                            float* __restrict__ l2) {
    __shared__ float ws[4][2];
    const int r0 = blockIdx.x * 2;
    const int t = threadIdx.x;
    const f4* __restrict__ w12r0 = reinterpret_cast<const f4*>(w12) + (size_t)r0 * (N1 / 4);
    const f4* __restrict__ w12r1 = w12r0 + (N1 / 4);
    const f4* __restrict__ w32r0 = reinterpret_cast<const f4*>(w32) + (size_t)r0 * (N3 / 4);
    const f4* __restrict__ w32r1 = w32r0 + (N3 / 4);
    const f4* __restrict__ x1 = reinterpret_cast<const f4*>(l1);
    const f4* __restrict__ x3 = reinterpret_cast<const f4*>(l3s);

    float a0 = 0.0f, a1 = 0.0f, b0 = 0.0f, b1 = 0.0f;
#pragma unroll
    for (int k = 0; k < (N1 / 4) / 256; ++k) {  // 8 iters
        const int i = t + k * 256;
        f4 x = x1[i];
        f4 u = __builtin_nontemporal_load(&w12r0[i]);
        f4 v = __builtin_nontemporal_load(&w12r1[i]);
        a0 = fmaf(u.x, x.x, fmaf(u.y, x.y, fmaf(u.z, x.z, fmaf(u.w, x.w, a0))));
        a1 = fmaf(v.x, x.x, fmaf(v.y, x.y, fmaf(v.z, x.z, fmaf(v.w, x.w, a1))));
    }
#pragma unroll
    for (int k = 0; k < (N3 / 4) / 256; ++k) {  // 2 iters
        const int i = t + k * 256;
        f4 x = x3[i];
        f4 u = __builtin_nontemporal_load(&w32r0[i]);
        f4 v = __builtin_nontemporal_load(&w32r1[i]);
        b0 = fmaf(u.x, x.x, fmaf(u.y, x.y, fmaf(u.z, x.z, fmaf(u.w, x.w, b0))));
        b1 = fmaf(v.x, x.x, fmaf(v.y, x.y, fmaf(v.z, x.z, fmaf(v.w, x.w, b1))));
    }
    float v0 = fmaf(0.3f, b0, a0);
    float v1 = fmaf(0.3f, b1, a1);
#pragma unroll
    for (int off = 32; off; off >>= 1) {
        v0 += __shfl_down(v0, off, 64);
        v1 += __shfl_down(v1, off, 64);
    }
    if ((t & 63) == 0) { ws[t >> 6][0] = v0; ws[t >> 6][1] = v1; }
    __syncthreads();
    if (t == 0) {
        float t0 = ws[0][0] + ws[1][0] + ws[2][0] + ws[3][0];
        float t1 = ws[0][1] + ws[1][1] + ws[2][1] + ws[3][1];
        l2[r0]     = 0.98f * l2s[r0]     + 0.02f * tanhf(t0);
        l2[r0 + 1] = 0.98f * l2s[r0 + 1] + 0.02f * tanhf(t1);
    }
}

// ---------- Kernel 3: TWO rows of w23 per block ----------
// l3[r] = 0.99*l3_state[r] + 0.01*tanh( w23[r,:]@l2 )
__global__ __launch_bounds__(256) void k_l3(const float* __restrict__ w23,
                                            const float* __restrict__ l2,
                                            const float* __restrict__ l3s,
                                            float* __restrict__ l3) {
    __shared__ float ws[4][2];
    const int r0 = blockIdx.x * 2;
    const int t = threadIdx.x;
    const f4* __restrict__ wr0 = reinterpret_cast<const f4*>(w23) + (size_t)r0 * (N2 / 4);
    const f4* __restrict__ wr1 = wr0 + (N2 / 4);
    const f4* __restrict__ x2 = reinterpret_cast<const f4*>(l2);

    float a0 = 0.0f, a1 = 0.0f;
#pragma unroll
    for (int k = 0; k < (N2 / 4) / 256; ++k) {  // 4 iters
        const int i = t + k * 256;
        f4 x = x2[i];
        f4 u = __builtin_nontemporal_load(&wr0[i]);
        f4 v = __builtin_nontemporal_load(&wr1[i]);
        a0 = fmaf(u.x, x.x, fmaf(u.y, x.y, fmaf(u.z, x.z, fmaf(u.w, x.w, a0))));
        a1 = fmaf(v.x, x.x, fmaf(v.y, x.y, fmaf(v.z, x.z, fmaf(v.w, x.w, a1))));
    }
#pragma unroll
    for (int off = 32; off; off >>= 1) {
        a0 += __shfl_down(a0, off, 64);
        a1 += __shfl_down(a1, off, 64);
    }
    if ((t & 63) == 0) { ws[t >> 6][0] = a0; ws[t >> 6][1] = a1; }
    __syncthreads();
    if (t == 0) {
        float t0 = ws[0][0] + ws[1][0] + ws[2][0] + ws[3][0];
        float t1 = ws[0][1] + ws[1][1] + ws[2][1] + ws[3][1];
        l3[r0]     = 0.99f * l3s[r0]     + 0.01f * tanhf(t0);
        l3[r0 + 1] = 0.99f * l3s[r0 + 1] + 0.01f * tanhf(t1);
    }
}

// ---------- Kernel 4: all scalar reductions, single block, 2 barriers ----------
// moments: [0]=sum|v| [1]=sum v [2]=sum v^2 over concat(l1,l2,l3)
//          [3..7]  = sx,sy,sxx,syy,sxy over (l1[:4096], l2)
//          [8..12] = sx,sy,sxx,syy,sxy over (l2[:2048], l3)
__global__ __launch_bounds__(1024) void k_fin(const float* __restrict__ out,
                                              const float* __restrict__ corr_in,
                                              const float* __restrict__ coh_in,
                                              float* __restrict__ scal) {
    __shared__ double sred[16][13];
    __shared__ double fin[13];
    const int t = threadIdx.x;
    const f4* __restrict__ o4 = reinterpret_cast<const f4*>(out);
    // element offsets (in f4 units): l1 @ 0 (2048), l2 @ 2048 (1024), l3 @ 3072 (512)

    double p[13];
#pragma unroll
    for (int j = 0; j < 13; ++j) p[j] = 0.0;

    for (int i = t; i < 3584; i += 1024) {  // all 14336 elems
        f4 v = o4[i];
#pragma unroll
        for (int c = 0; c < 4; ++c) {
            double d = (double)v[c];
            p[0] += fabs(d); p[1] += d; p[2] += d * d;
        }
    }
    {  // (l1[:4096], l2) — exactly 1024 f4 pairs
        f4 x = o4[t];
        f4 y = o4[2048 + t];
#pragma unroll
        for (int c = 0; c < 4; ++c) {
            double dx = (double)x[c], dy = (double)y[c];
            p[3] += dx; p[4] += dy; p[5] += dx * dx; p[6] += dy * dy; p[7] += dx * dy;
        }
    }
    if (t < 512) {  // (l2[:2048], l3) — 512 f4 pairs
        f4 x = o4[2048 + t];
        f4 y = o4[3072 + t];
#pragma unroll
        for (int c = 0; c < 4; ++c) {
            double dx = (double)x[c], dy = (double)y[c];
            p[8] += dx; p[9] += dy; p[10] += dx * dx; p[11] += dy * dy; p[12] += dx * dy;
        }
    }

    // 13 wave reductions back-to-back, then one LDS combine
#pragma unroll
    for (int j = 0; j < 13; ++j) {
        double v = p[j];
#pragma unroll
        for (int off = 32; off; off >>= 1) v += __shfl_down(v, off, 64);
        p[j] = v;
    }
    if ((t & 63) == 0) {
        const int w = t >> 6;
#pragma unroll
        for (int j = 0; j < 13; ++j) sred[w][j] = p[j];
    }
    __syncthreads();
    if (t < 13) {
        double s = 0.0;
#pragma unroll
        for (int w = 0; w < 16; ++w) s += sred[w][t];
        fin[t] = s;
    }
    __syncthreads();

    if (t == 0) {
        const double n12 = (double)N2;
        const double n23 = (double)N3;
        const double nall = (double)(N1 + N2 + N3);

        double sxy12 = fin[7] - fin[3] * fin[4] / n12;
        double sxx12 = fin[5] - fin[3] * fin[3] / n12;
        double syy12 = fin[6] - fin[4] * fin[4] / n12;
        double den12 = sqrt(sxx12 * syy12);
        double c12 = (den12 > 0.0 && isfinite(den12)) ? sxy12 / den12 : 0.0;

        double sxy23 = fin[12] - fin[8] * fin[9] / n23;
        double sxx23 = fin[10] - fin[8] * fin[8] / n23;
        double syy23 = fin[11] - fin[9] * fin[9] / n23;
        double den23 = sqrt(sxx23 * syy23);
        double c23 = (den23 > 0.0 && isfinite(den23)) ? sxy23 / den23 : 0.0;

        double corr_new = 0.9 * (double)corr_in[0] + 0.1 * (c12 + c23) * 0.5;

        double total = fin[0];
        double var = (fin[2] - fin[1] * fin[1] / nall) / (nall - 1.0);
        double coh = total / (var + 1e-6);
        coh = fmin(fmax(coh, 0.0), 10.0);
        double coh_new = 0.9 * (double)coh_in[0] + 0.1 * coh;

        scal[0] = (float)corr_new;
        scal[1] = (float)coh_new;
        scal[2] = (float)(total / nall);
    }
}

extern "C" void kernel_launch(void* const* d_in, const int* in_sizes, int n_in,
                              void* d_out, int out_size, void* d_ws, size_t ws_size,
                              hipStream_t stream) {
    const float* smi     = (const float*)d_in[0];
    const float* l1s     = (const float*)d_in[1];
    const float* l2s     = (const float*)d_in[2];
    const float* l3s     = (const float*)d_in[3];
    const float* w12     = (const float*)d_in[4];
    const float* w23     = (const float*)d_in[5];
    const float* w32     = (const float*)d_in[6];
    // d_in[7] = w21 is UNUSED by the reference — never read (saves 134 MB).
    const float* corr_in = (const float*)d_in[8];
    const float* coh_in  = (const float*)d_in[9];

    float* out = (float*)d_out;
    float* l1 = out;
    float* l2 = out + N1;
    float* l3 = out + N1 + N2;
    float* scal = out + N1 + N2 + N3;

    k_l1<<<dim3(N1 / 256), dim3(256), 0, stream>>>(smi, l1s, l1);
    k_l2<<<dim3(N2 / 2), dim3(256), 0, stream>>>(w12, w32, l1, l3s, l2s, l2);
    k_l3<<<dim3(N3 / 2), dim3(256), 0, stream>>>(w23, l2, l3s, l3);
    k_fin<<<dim3(1), dim3(1024), 0, stream>>>(out, corr_in, coh_in, scal);
}

// Round 4
// 48.607 us; speedup vs baseline: 2.3293x; 1.0270x over previous
//
#include <hip/hip_runtime.h>
#include <math.h>

#define N1 8192
#define N2 4096
#define N3 2048

typedef float f4 __attribute__((ext_vector_type(4)));

// ---------- Kernel 0 (k_pre): fused l1-update + w32@l3_state precompute ----------
// blocks [0,32):    l1 = 0.95*l1_state + 0.05*tanh(smi)      (8192 elems)
// blocks [32,1056): t2[r] = w32[r,:] @ l3_state, 4 rows/block (4096 rows)
__global__ __launch_bounds__(256) void k_pre(const float* __restrict__ smi,
                                             const float* __restrict__ l1s,
                                             float* __restrict__ l1,
                                             const float* __restrict__ w32,
                                             const float* __restrict__ l3s,
                                             float* __restrict__ t2) {
    const int b = blockIdx.x;
    const int t = threadIdx.x;
    if (b < 32) {
        const int i = b * 256 + t;
        l1[i] = 0.95f * l1s[i] + 0.05f * tanhf(smi[i]);
        return;
    }
    __shared__ float ws[4][4];
    const int r0 = (b - 32) * 4;
    const f4* __restrict__ w0 = reinterpret_cast<const f4*>(w32) + (size_t)r0 * (N3 / 4);
    const f4* __restrict__ w1 = w0 + (N3 / 4);
    const f4* __restrict__ w2 = w1 + (N3 / 4);
    const f4* __restrict__ w3 = w2 + (N3 / 4);
    const f4* __restrict__ x = reinterpret_cast<const f4*>(l3s);

    float a0 = 0.f, a1 = 0.f, a2 = 0.f, a3 = 0.f;
#pragma unroll
    for (int k = 0; k < (N3 / 4) / 256; ++k) {  // 2 iters
        const int i = t + k * 256;
        f4 xv = x[i];
        f4 u0 = __builtin_nontemporal_load(&w0[i]);
        f4 u1 = __builtin_nontemporal_load(&w1[i]);
        f4 u2 = __builtin_nontemporal_load(&w2[i]);
        f4 u3 = __builtin_nontemporal_load(&w3[i]);
        a0 = fmaf(u0.x, xv.x, fmaf(u0.y, xv.y, fmaf(u0.z, xv.z, fmaf(u0.w, xv.w, a0))));
        a1 = fmaf(u1.x, xv.x, fmaf(u1.y, xv.y, fmaf(u1.z, xv.z, fmaf(u1.w, xv.w, a1))));
        a2 = fmaf(u2.x, xv.x, fmaf(u2.y, xv.y, fmaf(u2.z, xv.z, fmaf(u2.w, xv.w, a2))));
        a3 = fmaf(u3.x, xv.x, fmaf(u3.y, xv.y, fmaf(u3.z, xv.z, fmaf(u3.w, xv.w, a3))));
    }
#pragma unroll
    for (int off = 32; off; off >>= 1) {
        a0 += __shfl_down(a0, off, 64);
        a1 += __shfl_down(a1, off, 64);
        a2 += __shfl_down(a2, off, 64);
        a3 += __shfl_down(a3, off, 64);
    }
    if ((t & 63) == 0) {
        const int w = t >> 6;
        ws[w][0] = a0; ws[w][1] = a1; ws[w][2] = a2; ws[w][3] = a3;
    }
    __syncthreads();
    if (t < 4) {
        t2[r0 + t] = ws[0][t] + ws[1][t] + ws[2][t] + ws[3][t];
    }
}

// ---------- Kernel 2: FOUR rows of w12 per block ----------
// l2[r] = 0.98*l2_state[r] + 0.02*tanh( w12[r,:]@l1 + 0.3*t2[r] )
__global__ __launch_bounds__(256) void k_l2(const float* __restrict__ w12,
                                            const float* __restrict__ l1,
                                            const float* __restrict__ t2,
                                            const float* __restrict__ l2s,
                                            float* __restrict__ l2) {
    __shared__ float ws[4][4];
    const int r0 = blockIdx.x * 4;
    const int t = threadIdx.x;
    const f4* __restrict__ w0 = reinterpret_cast<const f4*>(w12) + (size_t)r0 * (N1 / 4);
    const f4* __restrict__ w1 = w0 + (N1 / 4);
    const f4* __restrict__ w2 = w1 + (N1 / 4);
    const f4* __restrict__ w3 = w2 + (N1 / 4);
    const f4* __restrict__ x = reinterpret_cast<const f4*>(l1);

    float a0 = 0.f, a1 = 0.f, a2 = 0.f, a3 = 0.f;
#pragma unroll
    for (int k = 0; k < (N1 / 4) / 256; ++k) {  // 8 iters
        const int i = t + k * 256;
        f4 xv = x[i];
        f4 u0 = __builtin_nontemporal_load(&w0[i]);
        f4 u1 = __builtin_nontemporal_load(&w1[i]);
        f4 u2 = __builtin_nontemporal_load(&w2[i]);
        f4 u3 = __builtin_nontemporal_load(&w3[i]);
        a0 = fmaf(u0.x, xv.x, fmaf(u0.y, xv.y, fmaf(u0.z, xv.z, fmaf(u0.w, xv.w, a0))));
        a1 = fmaf(u1.x, xv.x, fmaf(u1.y, xv.y, fmaf(u1.z, xv.z, fmaf(u1.w, xv.w, a1))));
        a2 = fmaf(u2.x, xv.x, fmaf(u2.y, xv.y, fmaf(u2.z, xv.z, fmaf(u2.w, xv.w, a2))));
        a3 = fmaf(u3.x, xv.x, fmaf(u3.y, xv.y, fmaf(u3.z, xv.z, fmaf(u3.w, xv.w, a3))));
    }
#pragma unroll
    for (int off = 32; off; off >>= 1) {
        a0 += __shfl_down(a0, off, 64);
        a1 += __shfl_down(a1, off, 64);
        a2 += __shfl_down(a2, off, 64);
        a3 += __shfl_down(a3, off, 64);
    }
    if ((t & 63) == 0) {
        const int w = t >> 6;
        ws[w][0] = a0; ws[w][1] = a1; ws[w][2] = a2; ws[w][3] = a3;
    }
    __syncthreads();
    if (t < 4) {
        const int r = r0 + t;
        float tot = ws[0][t] + ws[1][t] + ws[2][t] + ws[3][t] + 0.3f * t2[r];
        l2[r] = 0.98f * l2s[r] + 0.02f * tanhf(tot);
    }
}

// ---------- Kernel 3: FOUR rows of w23 per block ----------
// l3[r] = 0.99*l3_state[r] + 0.01*tanh( w23[r,:]@l2 )
__global__ __launch_bounds__(256) void k_l3(const float* __restrict__ w23,
                                            const float* __restrict__ l2,
                                            const float* __restrict__ l3s,
                                            float* __restrict__ l3) {
    __shared__ float ws[4][4];
    const int r0 = blockIdx.x * 4;
    const int t = threadIdx.x;
    const f4* __restrict__ w0 = reinterpret_cast<const f4*>(w23) + (size_t)r0 * (N2 / 4);
    const f4* __restrict__ w1 = w0 + (N2 / 4);
    const f4* __restrict__ w2 = w1 + (N2 / 4);
    const f4* __restrict__ w3 = w2 + (N2 / 4);
    const f4* __restrict__ x = reinterpret_cast<const f4*>(l2);

    float a0 = 0.f, a1 = 0.f, a2 = 0.f, a3 = 0.f;
#pragma unroll
    for (int k = 0; k < (N2 / 4) / 256; ++k) {  // 4 iters
        const int i = t + k * 256;
        f4 xv = x[i];
        f4 u0 = __builtin_nontemporal_load(&w0[i]);
        f4 u1 = __builtin_nontemporal_load(&w1[i]);
        f4 u2 = __builtin_nontemporal_load(&w2[i]);
        f4 u3 = __builtin_nontemporal_load(&w3[i]);
        a0 = fmaf(u0.x, xv.x, fmaf(u0.y, xv.y, fmaf(u0.z, xv.z, fmaf(u0.w, xv.w, a0))));
        a1 = fmaf(u1.x, xv.x, fmaf(u1.y, xv.y, fmaf(u1.z, xv.z, fmaf(u1.w, xv.w, a1))));
        a2 = fmaf(u2.x, xv.x, fmaf(u2.y, xv.y, fmaf(u2.z, xv.z, fmaf(u2.w, xv.w, a2))));
        a3 = fmaf(u3.x, xv.x, fmaf(u3.y, xv.y, fmaf(u3.z, xv.z, fmaf(u3.w, xv.w, a3))));
    }
#pragma unroll
    for (int off = 32; off; off >>= 1) {
        a0 += __shfl_down(a0, off, 64);
        a1 += __shfl_down(a1, off, 64);
        a2 += __shfl_down(a2, off, 64);
        a3 += __shfl_down(a3, off, 64);
    }
    if ((t & 63) == 0) {
        const int w = t >> 6;
        ws[w][0] = a0; ws[w][1] = a1; ws[w][2] = a2; ws[w][3] = a3;
    }
    __syncthreads();
    if (t < 4) {
        const int r = r0 + t;
        float tot = ws[0][t] + ws[1][t] + ws[2][t] + ws[3][t];
        l3[r] = 0.99f * l3s[r] + 0.01f * tanhf(tot);
    }
}

// ---------- Kernel 4: all scalar reductions, single block, 2 barriers ----------
__global__ __launch_bounds__(1024) void k_fin(const float* __restrict__ out,
                                              const float* __restrict__ corr_in,
                                              const float* __restrict__ coh_in,
                                              float* __restrict__ scal) {
    __shared__ double sred[16][13];
    __shared__ double fin[13];
    const int t = threadIdx.x;
    const f4* __restrict__ o4 = reinterpret_cast<const f4*>(out);
    // f4 offsets: l1 @ 0 (2048), l2 @ 2048 (1024), l3 @ 3072 (512)

    double p[13];
#pragma unroll
    for (int j = 0; j < 13; ++j) p[j] = 0.0;

    for (int i = t; i < 3584; i += 1024) {  // all 14336 elems
        f4 v = o4[i];
#pragma unroll
        for (int c = 0; c < 4; ++c) {
            double d = (double)v[c];
            p[0] += fabs(d); p[1] += d; p[2] += d * d;
        }
    }
    {  // (l1[:4096], l2)
        f4 x = o4[t];
        f4 y = o4[2048 + t];
#pragma unroll
        for (int c = 0; c < 4; ++c) {
            double dx = (double)x[c], dy = (double)y[c];
            p[3] += dx; p[4] += dy; p[5] += dx * dx; p[6] += dy * dy; p[7] += dx * dy;
        }
    }
    if (t < 512) {  // (l2[:2048], l3)
        f4 x = o4[2048 + t];
        f4 y = o4[3072 + t];
#pragma unroll
        for (int c = 0; c < 4; ++c) {
            double dx = (double)x[c], dy = (double)y[c];
            p[8] += dx; p[9] += dy; p[10] += dx * dx; p[11] += dy * dy; p[12] += dx * dy;
        }
    }

#pragma unroll
    for (int j = 0; j < 13; ++j) {
        double v = p[j];
#pragma unroll
        for (int off = 32; off; off >>= 1) v += __shfl_down(v, off, 64);
        p[j] = v;
    }
    if ((t & 63) == 0) {
        const int w = t >> 6;
#pragma unroll
        for (int j = 0; j < 13; ++j) sred[w][j] = p[j];
    }
    __syncthreads();
    if (t < 13) {
        double s = 0.0;
#pragma unroll
        for (int w = 0; w < 16; ++w) s += sred[w][t];
        fin[t] = s;
    }
    __syncthreads();

    if (t == 0) {
        const double n12 = (double)N2;
        const double n23 = (double)N3;
        const double nall = (double)(N1 + N2 + N3);

        double sxy12 = fin[7] - fin[3] * fin[4] / n12;
        double sxx12 = fin[5] - fin[3] * fin[3] / n12;
        double syy12 = fin[6] - fin[4] * fin[4] / n12;
        double den12 = sqrt(sxx12 * syy12);
        double c12 = (den12 > 0.0 && isfinite(den12)) ? sxy12 / den12 : 0.0;

        double sxy23 = fin[12] - fin[8] * fin[9] / n23;
        double sxx23 = fin[10] - fin[8] * fin[8] / n23;
        double syy23 = fin[11] - fin[9] * fin[9] / n23;
        double den23 = sqrt(sxx23 * syy23);
        double c23 = (den23 > 0.0 && isfinite(den23)) ? sxy23 / den23 : 0.0;

        double corr_new = 0.9 * (double)corr_in[0] + 0.1 * (c12 + c23) * 0.5;

        double total = fin[0];
        double var = (fin[2] - fin[1] * fin[1] / nall) / (nall - 1.0);
        double coh = total / (var + 1e-6);
        coh = fmin(fmax(coh, 0.0), 10.0);
        double coh_new = 0.9 * (double)coh_in[0] + 0.1 * coh;

        scal[0] = (float)corr_new;
        scal[1] = (float)coh_new;
        scal[2] = (float)(total / nall);
    }
}

extern "C" void kernel_launch(void* const* d_in, const int* in_sizes, int n_in,
                              void* d_out, int out_size, void* d_ws, size_t ws_size,
                              hipStream_t stream) {
    const float* smi     = (const float*)d_in[0];
    const float* l1s     = (const float*)d_in[1];
    const float* l2s     = (const float*)d_in[2];
    const float* l3s     = (const float*)d_in[3];
    const float* w12     = (const float*)d_in[4];
    const float* w23     = (const float*)d_in[5];
    const float* w32     = (const float*)d_in[6];
    // d_in[7] = w21 is UNUSED by the reference — never read (saves 134 MB).
    const float* corr_in = (const float*)d_in[8];
    const float* coh_in  = (const float*)d_in[9];

    float* out = (float*)d_out;
    float* l1 = out;
    float* l2 = out + N1;
    float* l3 = out + N1 + N2;
    float* scal = out + N1 + N2 + N3;
    float* t2 = (float*)d_ws;  // 4096 floats of scratch

    k_pre<<<dim3(32 + N2 / 4), dim3(256), 0, stream>>>(smi, l1s, l1, w32, l3s, t2);
    k_l2<<<dim3(N2 / 4), dim3(256), 0, stream>>>(w12, l1, t2, l2s, l2);
    k_l3<<<dim3(N3 / 4), dim3(256), 0, stream>>>(w23, l2, l3s, l3);
    k_fin<<<dim3(1), dim3(1024), 0, stream>>>(out, corr_in, coh_in, scal);
}